// Round 18
// baseline (49.716 us; speedup 1.0000x reference)
//
#include <hip/hip_runtime.h>
#include <math.h>

// Problem constants (fixed by reference setup_inputs)
#define B_SZ 64
#define N_IN 1024
#define IDIM 64
#define NC   16
#define DC   32
#define NQ0  4      // K0 blocks per batch (colsum)
#define NQ   8      // K1/K2 blocks per batch
#define QR   128    // rows per K1/K2 block
#define NTHR 512    // 8 waves
#define XS   68     // xT row stride [n][i]: 68%32=4 -> b128 floor patterns
#define AS   20     // aSmT / pSm / wSm row stride

// Workspace (floats). NOTHING needs zero-init; no atomics, no counters,
// no spin barriers. All cross-block reductions cross kernel boundaries.
//  cs  : [64][4][64]   @ 0       colsum partials (plain)
//  sp1 : [64][8][1024] @ 16384   xs partials iter 1 (plain)
//  sp2 : [64][8][1024] @ 540672  xs partials iter 2 (plain)
//  wv0 : [64][1024]    @ 1064960 wv(v0) (plain; q0 writes in K1, read in K2)
#define WS_CS  0
#define WS_SP1 16384
#define WS_SP2 540672
#define WS_WV0 1064960

__device__ __forceinline__ float rdlane_f(float v, int l) {
    return __int_as_float(__builtin_amdgcn_readlane(__float_as_int(v), l));
}

// ---- shared building blocks ----

// stage 128 rows into [n][i] tile: 4 conflict-free ds_write_b128/thread
__device__ __forceinline__ void stage_x(const float* __restrict__ x, float* xT,
                                        int b, int q, int tid) {
    const float4* xb4 = reinterpret_cast<const float4*>(x + ((size_t)b * N_IN + q * QR) * IDIM);
#pragma unroll
    for (int m = 0; m < 4; m++) {
        const int f = tid + m * NTHR;
        const float4 v4 = xb4[f];
        const int n = f >> 4, i0 = (f & 15) * 4;
        *reinterpret_cast<float4*>(&xT[n * XS + i0]) = v4;
    }
}

// routing pass (512 thr): agreement(b128+readlane) -> softmax -> xs(readlane)
// Outputs vA (o = tid) and vB (o = tid + 512), o = c*64 + i.
__device__ __forceinline__ void route_pass(const float* xT, const float* wSm,
                                           float* aSmT, float* pSm,
                                           int tid, int lane, int wave,
                                           int row, int grp, int rq,
                                           float& vA, float& vB) {
    const float4 wr4 = *reinterpret_cast<const float4*>(&wSm[lane * AS + grp * 4]);
    {   // agreement: caps grp*4..+3 for row; 16 b128 + readlane-fma
        float a0 = 0.f, a1 = 0.f, a2 = 0.f, a3 = 0.f;
#pragma unroll
        for (int iq = 0; iq < 16; iq++) {
            const float4 xv = *reinterpret_cast<const float4*>(&xT[row * XS + iq * 4]);
#pragma unroll
            for (int j = 0; j < 4; j++) {
                const int i = iq * 4 + j;
                const float xc = (j == 0) ? xv.x : (j == 1) ? xv.y
                               : (j == 2) ? xv.z : xv.w;
                a0 += rdlane_f(wr4.x, i) * xc;
                a1 += rdlane_f(wr4.y, i) * xc;
                a2 += rdlane_f(wr4.z, i) * xc;
                a3 += rdlane_f(wr4.w, i) * xc;
            }
        }
        *reinterpret_cast<float4*>(&aSmT[row * AS + grp * 4]) =
            make_float4(a0, a1, a2, a3);
    }
    __syncthreads();
    // softmax over 16 caps per row; cw via uniform grp if-chain (regs only)
    float cw0, cw1, cw2, cw3;
    {
        const float4 q0 = *reinterpret_cast<const float4*>(&aSmT[row * AS + 0]);
        const float4 q1 = *reinterpret_cast<const float4*>(&aSmT[row * AS + 4]);
        const float4 q2 = *reinterpret_cast<const float4*>(&aSmT[row * AS + 8]);
        const float4 q3 = *reinterpret_cast<const float4*>(&aSmT[row * AS + 12]);
        float av[NC] = {q0.x, q0.y, q0.z, q0.w, q1.x, q1.y, q1.z, q1.w,
                        q2.x, q2.y, q2.z, q2.w, q3.x, q3.y, q3.z, q3.w};
        float mx = av[0];
#pragma unroll
        for (int k = 1; k < NC; k++) mx = fmaxf(mx, av[k]);
        float ss = 0.f;
#pragma unroll
        for (int k = 0; k < NC; k++) { av[k] = __expf(av[k] - mx); ss += av[k]; }
        const float inv = 1.f / ss;
        if (grp == 0)      { cw0 = av[0];  cw1 = av[1];  cw2 = av[2];  cw3 = av[3];  }
        else if (grp == 1) { cw0 = av[4];  cw1 = av[5];  cw2 = av[6];  cw3 = av[7];  }
        else if (grp == 2) { cw0 = av[8];  cw1 = av[9];  cw2 = av[10]; cw3 = av[11]; }
        else               { cw0 = av[12]; cw1 = av[13]; cw2 = av[14]; cw3 = av[15]; }
        cw0 *= inv; cw1 *= inv; cw2 *= inv; cw3 *= inv;
    }
    // xs: NO sync (reads xT + same-wave regs). wave (grp = wave>>1, rq = wave&1):
    // caps grp*4..+3, rows rq*64..+63, lane = i. cw for row rq*64+nl: thread
    // tid' = grp*128 + rq*64 + nl = wave*64 + nl -> lane nl of THIS wave.
    {
        float s0 = 0.f, s1 = 0.f, s2 = 0.f, s3 = 0.f;
#pragma unroll
        for (int nl = 0; nl < 64; nl++) {
            const float xv = xT[(rq * 64 + nl) * XS + lane];   // coalesced b32
            s0 += rdlane_f(cw0, nl) * xv;
            s1 += rdlane_f(cw1, nl) * xv;
            s2 += rdlane_f(cw2, nl) * xv;
            s3 += rdlane_f(cw3, nl) * xv;
        }
        *reinterpret_cast<float4*>(&pSm[(rq * 64 + lane) * AS + grp * 4]) =
            make_float4(s0, s1, s2, s3);
    }
    __syncthreads();
    // reduce the 2 rq partials; thread covers o = tid (c = tid>>6) and o+512
    const int io = tid & 63, co = tid >> 6;                    // co 0..7
    vA = pSm[io * AS + co]       + pSm[(64 + io) * AS + co];
    vB = pSm[io * AS + (co + 8)] + pSm[(64 + io) * AS + (co + 8)];
}

// s = red @ W[c] (+scale) -> squash -> vSm (or out); needs >=512 threads
__device__ __forceinline__ void caps_sv(const float* __restrict__ W, const float* redSm,
                                        float* vSm, int tid, bool modeRed0, bool toOut,
                                        float* __restrict__ outp, int b) {
    if (tid < 512) {
        const int c = tid >> 5, dd = tid & 31;
        const float* Wc = W + c * (IDIM * DC) + dd;
        float s = 0.f;
#pragma unroll 8
        for (int i = 0; i < IDIM; i++) {
            const float rv = modeRed0 ? redSm[i] : redSm[c * 64 + i];
            s += rv * Wc[i * DC];
        }
        if (modeRed0) s *= 0.0625f;
        float n2 = s * s;
#pragma unroll
        for (int m = 16; m >= 1; m >>= 1) n2 += __shfl_xor(n2, m);  // 32-lane half
        const float g = (n2 / (1.f + n2)) / (sqrtf(n2) + 1e-8f);
        if (toOut) outp[b * (NC * DC) + c * DC + dd] = g * s;
        else       vSm[c * 36 + dd] = g * s;
    }
    __syncthreads();
}

// wv for i = (tid>>4) + 32h, c = tid&15; h=0 -> flat index tid, h=1 -> tid+512
__device__ __forceinline__ float caps_wv_h(const float* __restrict__ W, const float* vSm,
                                           int tid, int h) {
    const int i = (tid >> 4) + 32 * h, c = tid & 15;
    const float4* Wr = reinterpret_cast<const float4*>(W + (size_t)(c * IDIM + i) * DC);
    const float4* vv = reinterpret_cast<const float4*>(&vSm[c * 36]);
    float acc = 0.f;
#pragma unroll
    for (int dq = 0; dq < 8; dq++) {
        const float4 wq = Wr[dq], vq = vv[dq];
        acc += wq.x * vq.x + wq.y * vq.y + wq.z * vq.z + wq.w * vq.w;
    }
    return acc;
}

// ---- K0: colsum partials straight from global (streams x, warms L3)
__global__ __launch_bounds__(256) void k_colsum(const float* __restrict__ x,
                                                float* __restrict__ cs) {
    const int b = blockIdx.y, q = blockIdx.x;
    const int tid = threadIdx.x;
    const float4* xb4 = reinterpret_cast<const float4*>(x + ((size_t)b * N_IN + q * 256) * IDIM);
    float4 s4 = {0.f, 0.f, 0.f, 0.f};
#pragma unroll
    for (int m = 0; m < 16; m++) {
        const float4 v4 = xb4[tid + m * 256];
        s4.x += v4.x; s4.y += v4.y; s4.z += v4.z; s4.w += v4.w;
    }
    __shared__ float red[16][64];
    const int g = tid >> 4, i0 = (tid & 15) * 4;
    red[g][i0 + 0] = s4.x; red[g][i0 + 1] = s4.y;
    red[g][i0 + 2] = s4.z; red[g][i0 + 3] = s4.w;
    __syncthreads();
    if (tid < 64) {
        float r = 0.f;
#pragma unroll
        for (int k = 0; k < 16; k++) r += red[k][tid];
        cs[(b * NQ0 + q) * 64 + tid] = r;
    }
}

// ---- K1: stage + reduce cs -> caps0 -> route1 -> sp1 (all plain)
__global__ __launch_bounds__(NTHR, 4)
void k_iter1(const float* __restrict__ x, const float* __restrict__ W,
             const float* __restrict__ cs, float* __restrict__ sp1,
             float* __restrict__ wv0) {
    const int b = blockIdx.x & 63, q = blockIdx.x >> 6;   // XCD co-location
    const int tid = threadIdx.x, lane = tid & 63, wave = tid >> 6;
    const int row = tid & 127, grp = tid >> 7, rq = wave & 1;

    __shared__ float __align__(16) xT[QR * XS];       // 34.8 KB
    __shared__ float __align__(16) aSmT[QR * AS];     // 10.2 KB
    __shared__ float __align__(16) pSm[QR * AS];      // 10.2 KB
    __shared__ float __align__(16) wSm[IDIM * AS];    // 5.1 KB
    __shared__ float redSm[NC * IDIM];                // 4 KB
    __shared__ float __align__(16) vSm[NC * 36];      // 2.3 KB  (total ~66.6 KB)

    stage_x(x, xT, b, q, tid);                 // L3-warm from K0
    if (tid < 64) {
        float r = 0.f;
#pragma unroll
        for (int k = 0; k < NQ0; k++) r += cs[(b * NQ0 + k) * 64 + tid];
        redSm[tid] = r;
    }
    __syncthreads();
    caps_sv(W, redSm, vSm, tid, true, false, nullptr, b);
#pragma unroll
    for (int h = 0; h < 2; h++) {
        const float acc = caps_wv_h(W, vSm, tid, h);
        const int i = (tid >> 4) + 32 * h, c = tid & 15;
        wSm[i * AS + c] = acc;
        if (q == 0) wv0[b * 1024 + tid + h * 512] = acc;   // flat idx = i*16+c
    }
    __syncthreads();
    float vA, vB;
    route_pass(xT, wSm, aSmT, pSm, tid, lane, wave, row, grp, rq, vA, vB);
    float* spq = sp1 + (size_t)(b * NQ + q) * 1024;
    spq[tid] = vA;
    spq[tid + 512] = vB;
}

// ---- K2: stage + reduce sp1 -> caps1 (wv_eff = wv(v1)+wv0) -> route2 -> sp2
__global__ __launch_bounds__(NTHR, 4)
void k_iter2(const float* __restrict__ x, const float* __restrict__ W,
             const float* __restrict__ sp1, float* __restrict__ sp2,
             const float* __restrict__ wv0) {
    const int b = blockIdx.x & 63, q = blockIdx.x >> 6;
    const int tid = threadIdx.x, lane = tid & 63, wave = tid >> 6;
    const int row = tid & 127, grp = tid >> 7, rq = wave & 1;

    __shared__ float __align__(16) xT[QR * XS];
    __shared__ float __align__(16) aSmT[QR * AS];
    __shared__ float __align__(16) pSm[QR * AS];
    __shared__ float __align__(16) wSm[IDIM * AS];
    __shared__ float redSm[NC * IDIM];
    __shared__ float __align__(16) vSm[NC * 36];

    stage_x(x, xT, b, q, tid);                 // same mapping -> L2-resident
    {
        float r0 = 0.f, r1 = 0.f;
#pragma unroll
        for (int k = 0; k < NQ; k++) {
            const float* s = sp1 + (size_t)(b * NQ + k) * 1024;
            r0 += s[tid];
            r1 += s[tid + 512];
        }
        redSm[tid] = r0;
        redSm[tid + 512] = r1;
    }
    __syncthreads();
    caps_sv(W, redSm, vSm, tid, false, false, nullptr, b);
#pragma unroll
    for (int h = 0; h < 2; h++) {
        const float acc = caps_wv_h(W, vSm, tid, h);
        const int i = (tid >> 4) + 32 * h, c = tid & 15;
        wSm[i * AS + c] = acc + wv0[b * 1024 + tid + h * 512];
    }
    __syncthreads();
    float vA, vB;
    route_pass(xT, wSm, aSmT, pSm, tid, lane, wave, row, grp, rq, vA, vB);
    float* spq = sp2 + (size_t)(b * NQ + q) * 1024;
    spq[tid] = vA;
    spq[tid + 512] = vB;
}

// ---- K3: reduce sp2 -> final squash -> out
__global__ __launch_bounds__(1024) void k_final(const float* __restrict__ sp2,
                                                const float* __restrict__ W,
                                                float* __restrict__ out) {
    const int b = blockIdx.x, tid = threadIdx.x;
    __shared__ float redSm[NC * IDIM];
    __shared__ float __align__(16) vSm[NC * 36];
    {
        float r = 0.f;
#pragma unroll
        for (int k = 0; k < NQ; k++) r += sp2[(size_t)(b * NQ + k) * 1024 + tid];
        redSm[tid] = r;
    }
    __syncthreads();
    caps_sv(W, redSm, vSm, tid, false, true, out, b);
}

extern "C" void kernel_launch(void* const* d_in, const int* in_sizes, int n_in,
                              void* d_out, int out_size, void* d_ws, size_t ws_size,
                              hipStream_t stream) {
    const float* x = (const float*)d_in[0];    // [64,1024,64]
    const float* W = (const float*)d_in[1];    // [16,64,32]
    float* out = (float*)d_out;                // [64,16,32]
    float* ws = (float*)d_ws;

    float* cs  = ws + WS_CS;
    float* sp1 = ws + WS_SP1;
    float* sp2 = ws + WS_SP2;
    float* wv0 = ws + WS_WV0;

    k_colsum<<<dim3(NQ0, B_SZ), 256, 0, stream>>>(x, cs);
    k_iter1<<<B_SZ * NQ, NTHR, 0, stream>>>(x, W, cs, sp1, wv0);
    k_iter2<<<B_SZ * NQ, NTHR, 0, stream>>>(x, W, sp1, sp2, wv0);
    k_final<<<B_SZ, 1024, 0, stream>>>(sp2, W, out);
}

// Round 19
// 45.354 us; speedup vs baseline: 1.0962x; 1.0962x over previous
//
#include <hip/hip_runtime.h>
#include <math.h>

// Problem constants (fixed by reference setup_inputs)
#define B_SZ 64
#define N_IN 1024
#define IDIM 64
#define NC   16
#define DC   32
#define NQ   4      // blocks per batch (K1/K2); also K0 chunks per batch
#define QR   256    // rows per block
#define NTHR 1024   // 16 waves
#define XS   68     // xT row stride [n][i]: 68%32=4 -> b128 floor patterns
#define AS   20     // aSmT / pSm / wSm row stride

// Workspace (floats):
//  cnt : 64*16 ints  @ 0       per-batch counters (1 cacheline apart; K0 re-arms)
//  cs  : [64][4][64]   @ 1024    colsum partials (plain; boundary-synced)
//  sp1 : [64][4][1024] @ 17408   xs partials iter 1 (plain; boundary-synced)
//  sp2 : [64][4][1024] @ 279552  xs partials iter 2 (agent; consumed in K2 tail)
//  wv0 : [64][1024]    @ 541696  wv(v0) (plain; q0 writes in K1, read in K2)
#define WS_CNT 0
#define WS_CS  1024
#define WS_SP1 17408
#define WS_SP2 279552
#define WS_WV0 541696

__device__ __forceinline__ void st_agent(float* p, float v) {
    __hip_atomic_store(p, v, __ATOMIC_RELAXED, __HIP_MEMORY_SCOPE_AGENT);
}
__device__ __forceinline__ float ld_agent(const float* p) {
    return __hip_atomic_load(p, __ATOMIC_RELAXED, __HIP_MEMORY_SCOPE_AGENT);
}
__device__ __forceinline__ float rdlane_f(float v, int l) {
    return __int_as_float(__builtin_amdgcn_readlane(__float_as_int(v), l));
}

// ---- shared building blocks (round-12/16/17-proven inner code) ----

// stage 256 rows into [n][i] tile: 4 conflict-free ds_write_b128/thread
__device__ __forceinline__ void stage_x(const float* __restrict__ x, float* xT,
                                        int b, int q, int tid) {
    const float4* xb4 = reinterpret_cast<const float4*>(x + ((size_t)b * N_IN + q * QR) * IDIM);
#pragma unroll
    for (int m = 0; m < 4; m++) {
        const int f = tid + m * NTHR;
        const float4 v4 = xb4[f];
        const int n = f >> 4, i0 = (f & 15) * 4;
        *reinterpret_cast<float4*>(&xT[n * XS + i0]) = v4;
    }
}

// routing pass: agreement(b128+readlane) -> softmax(regs) -> xs(readlane) -> val
__device__ __forceinline__ float route_pass(const float* xT, const float* wSm,
                                            float* aSmT, float* pSm,
                                            int tid, int lane, int wave,
                                            int row, int grp, int rq) {
    const float4 wr4 = *reinterpret_cast<const float4*>(&wSm[lane * AS + grp * 4]);
    {   // agreement: caps grp*4..+3 for row; 16 b128 + readlane-fma
        float a0 = 0.f, a1 = 0.f, a2 = 0.f, a3 = 0.f;
#pragma unroll
        for (int iq = 0; iq < 16; iq++) {
            const float4 xv = *reinterpret_cast<const float4*>(&xT[row * XS + iq * 4]);
#pragma unroll
            for (int j = 0; j < 4; j++) {
                const int i = iq * 4 + j;
                const float xc = (j == 0) ? xv.x : (j == 1) ? xv.y
                               : (j == 2) ? xv.z : xv.w;
                a0 += rdlane_f(wr4.x, i) * xc;
                a1 += rdlane_f(wr4.y, i) * xc;
                a2 += rdlane_f(wr4.z, i) * xc;
                a3 += rdlane_f(wr4.w, i) * xc;
            }
        }
        *reinterpret_cast<float4*>(&aSmT[row * AS + grp * 4]) =
            make_float4(a0, a1, a2, a3);
    }
    __syncthreads();
    // softmax over 16 caps per row; cw via uniform grp if-chain (regs only)
    float cw0, cw1, cw2, cw3;
    {
        const float4 q0 = *reinterpret_cast<const float4*>(&aSmT[row * AS + 0]);
        const float4 q1 = *reinterpret_cast<const float4*>(&aSmT[row * AS + 4]);
        const float4 q2 = *reinterpret_cast<const float4*>(&aSmT[row * AS + 8]);
        const float4 q3 = *reinterpret_cast<const float4*>(&aSmT[row * AS + 12]);
        float av[NC] = {q0.x, q0.y, q0.z, q0.w, q1.x, q1.y, q1.z, q1.w,
                        q2.x, q2.y, q2.z, q2.w, q3.x, q3.y, q3.z, q3.w};
        float mx = av[0];
#pragma unroll
        for (int k = 1; k < NC; k++) mx = fmaxf(mx, av[k]);
        float ss = 0.f;
#pragma unroll
        for (int k = 0; k < NC; k++) { av[k] = __expf(av[k] - mx); ss += av[k]; }
        const float inv = 1.f / ss;
        if (grp == 0)      { cw0 = av[0];  cw1 = av[1];  cw2 = av[2];  cw3 = av[3];  }
        else if (grp == 1) { cw0 = av[4];  cw1 = av[5];  cw2 = av[6];  cw3 = av[7];  }
        else if (grp == 2) { cw0 = av[8];  cw1 = av[9];  cw2 = av[10]; cw3 = av[11]; }
        else               { cw0 = av[12]; cw1 = av[13]; cw2 = av[14]; cw3 = av[15]; }
        cw0 *= inv; cw1 *= inv; cw2 *= inv; cw3 *= inv;
    }
    // xs: NO sync (reads xT + same-wave regs). wave (grp, rq): caps grp*4..+3,
    // rows rq*64..+63, lane = i; cw for row rq*64+nl lives in lane nl.
    {
        float s0 = 0.f, s1 = 0.f, s2 = 0.f, s3 = 0.f;
#pragma unroll
        for (int nl = 0; nl < 64; nl++) {
            const float xv = xT[(rq * 64 + nl) * XS + lane];   // coalesced b32
            s0 += rdlane_f(cw0, nl) * xv;
            s1 += rdlane_f(cw1, nl) * xv;
            s2 += rdlane_f(cw2, nl) * xv;
            s3 += rdlane_f(cw3, nl) * xv;
        }
        *reinterpret_cast<float4*>(&pSm[(rq * 64 + lane) * AS + grp * 4]) =
            make_float4(s0, s1, s2, s3);
    }
    __syncthreads();
    // reduce the 4 rq partials: thread (c = wave, i = lane) -> val for o = tid
    return pSm[(0 * 64 + lane) * AS + wave] + pSm[(1 * 64 + lane) * AS + wave] +
           pSm[(2 * 64 + lane) * AS + wave] + pSm[(3 * 64 + lane) * AS + wave];
}

// s = red @ W[c] (+scale) -> squash -> vSm (or out)
__device__ __forceinline__ void caps_sv(const float* __restrict__ W, const float* redSm,
                                        float* vSm, int tid, bool modeRed0, bool toOut,
                                        float* __restrict__ outp, int b) {
    if (tid < 512) {
        const int c = tid >> 5, dd = tid & 31;
        const float* Wc = W + c * (IDIM * DC) + dd;
        float s = 0.f;
#pragma unroll 8
        for (int i = 0; i < IDIM; i++) {
            const float rv = modeRed0 ? redSm[i] : redSm[c * 64 + i];
            s += rv * Wc[i * DC];
        }
        if (modeRed0) s *= 0.0625f;
        float n2 = s * s;
#pragma unroll
        for (int m = 16; m >= 1; m >>= 1) n2 += __shfl_xor(n2, m);  // 32-lane half
        const float g = (n2 / (1.f + n2)) / (sqrtf(n2) + 1e-8f);
        if (toOut) outp[b * (NC * DC) + c * DC + dd] = g * s;
        else       vSm[c * 36 + dd] = g * s;
    }
    __syncthreads();
}

__device__ __forceinline__ float caps_wv(const float* __restrict__ W, const float* vSm,
                                         int tid) {
    const int i = tid >> 4, c = tid & 15;   // 64 i x 16 c; out index == tid
    const float4* Wr = reinterpret_cast<const float4*>(W + (size_t)(c * IDIM + i) * DC);
    const float4* vv = reinterpret_cast<const float4*>(&vSm[c * 36]);
    float acc = 0.f;
#pragma unroll
    for (int dq = 0; dq < 8; dq++) {
        const float4 wq = Wr[dq], vq = vv[dq];
        acc += wq.x * vq.x + wq.y * vq.y + wq.z * vq.z + wq.w * vq.w;
    }
    return acc;
}

// ---- K0: colsum partials from global (streams x, warms L3) + counter re-arm
__global__ __launch_bounds__(256) void k_colsum(const float* __restrict__ x,
                                                float* __restrict__ cs,
                                                int* __restrict__ cnt) {
    const int b = blockIdx.y, q = blockIdx.x;
    const int tid = threadIdx.x;
    if (q == 0 && tid == 0) cnt[b * 16] = 0;   // re-arm per call; K0->K2 boundary orders it
    const float4* xb4 = reinterpret_cast<const float4*>(x + ((size_t)b * N_IN + q * QR) * IDIM);
    float4 s4 = {0.f, 0.f, 0.f, 0.f};
#pragma unroll
    for (int m = 0; m < 16; m++) {
        const float4 v4 = xb4[tid + m * 256];
        s4.x += v4.x; s4.y += v4.y; s4.z += v4.z; s4.w += v4.w;
    }
    __shared__ float red[16][64];
    const int g = tid >> 4, i0 = (tid & 15) * 4;
    red[g][i0 + 0] = s4.x; red[g][i0 + 1] = s4.y;
    red[g][i0 + 2] = s4.z; red[g][i0 + 3] = s4.w;
    __syncthreads();
    if (tid < 64) {
        float r = 0.f;
#pragma unroll
        for (int k = 0; k < 16; k++) r += red[k][tid];
        cs[(b * NQ + q) * 64 + tid] = r;
    }
}

// ---- K1: stage + reduce cs -> caps0 -> route1 -> sp1 (all plain)
__global__ __launch_bounds__(NTHR, 1)
void k_iter1(const float* __restrict__ x, const float* __restrict__ W,
             const float* __restrict__ cs, float* __restrict__ sp1,
             float* __restrict__ wv0) {
    const int b = blockIdx.x & 63, q = blockIdx.x >> 6;   // XCD co-location
    const int tid = threadIdx.x, lane = tid & 63, wave = tid >> 6;
    const int row = tid & 255, grp = tid >> 8, rq = wave & 3;

    __shared__ float __align__(16) xT[QR * XS];
    __shared__ float __align__(16) aSmT[QR * AS];
    __shared__ float __align__(16) pSm[4 * 64 * AS];
    __shared__ float __align__(16) wSm[IDIM * AS];
    __shared__ float redSm[NC * IDIM];
    __shared__ float __align__(16) vSm[NC * 36];

    stage_x(x, xT, b, q, tid);                 // L3-warm from K0
    if (tid < 64) {
        float r = 0.f;
#pragma unroll
        for (int k = 0; k < NQ; k++) r += cs[(b * NQ + k) * 64 + tid];
        redSm[tid] = r;
    }
    __syncthreads();
    caps_sv(W, redSm, vSm, tid, true, false, nullptr, b);
    {
        const float acc = caps_wv(W, vSm, tid);
        wSm[(tid >> 4) * AS + (tid & 15)] = acc;
        if (q == 0) wv0[b * 1024 + tid] = acc;
    }
    __syncthreads();
    const float val = route_pass(xT, wSm, aSmT, pSm, tid, lane, wave, row, grp, rq);
    sp1[(size_t)(b * NQ + q) * 1024 + tid] = val;
}

// ---- K2: stage + reduce sp1 -> caps1 (wv_eff = wv(v1)+wv0) -> route2 -> sp2
//      (agent) -> arrive; q0 tail: spin to NQ -> reduce -> final squash -> out
__global__ __launch_bounds__(NTHR, 1)
void k_iter2(const float* __restrict__ x, const float* __restrict__ W,
             float* __restrict__ out, int* __restrict__ cnt,
             const float* __restrict__ sp1, float* __restrict__ sp2,
             const float* __restrict__ wv0) {
    const int b = blockIdx.x & 63, q = blockIdx.x >> 6;
    const int tid = threadIdx.x, lane = tid & 63, wave = tid >> 6;
    const int row = tid & 255, grp = tid >> 8, rq = wave & 3;

    __shared__ float __align__(16) xT[QR * XS];
    __shared__ float __align__(16) aSmT[QR * AS];
    __shared__ float __align__(16) pSm[4 * 64 * AS];
    __shared__ float __align__(16) wSm[IDIM * AS];
    __shared__ float redSm[NC * IDIM];
    __shared__ float __align__(16) vSm[NC * 36];

    stage_x(x, xT, b, q, tid);                 // same grid mapping -> L2-resident
    {
        float r = 0.f;
#pragma unroll
        for (int k = 0; k < NQ; k++) r += sp1[(size_t)(b * NQ + k) * 1024 + tid];
        redSm[tid] = r;
    }
    __syncthreads();
    caps_sv(W, redSm, vSm, tid, false, false, nullptr, b);
    wSm[(tid >> 4) * AS + (tid & 15)] = caps_wv(W, vSm, tid) + wv0[b * 1024 + tid];
    __syncthreads();
    const float val = route_pass(xT, wSm, aSmT, pSm, tid, lane, wave, row, grp, rq);
    st_agent(&sp2[(size_t)(b * NQ + q) * 1024 + tid], val);

    __syncthreads();                      // drains sp2 stores before signal
    if (tid == 0)
        __hip_atomic_fetch_add(&cnt[b * 16], 1, __ATOMIC_RELEASE, __HIP_MEMORY_SCOPE_AGENT);
    if (q != 0) return;                   // producers never wait -> deadlock-free
    if (tid == 0)
        while (__hip_atomic_load(&cnt[b * 16], __ATOMIC_ACQUIRE,
                                 __HIP_MEMORY_SCOPE_AGENT) < NQ)
            __builtin_amdgcn_s_sleep(1);
    __syncthreads();
    {
        float r = val;                    // own partial from registers
#pragma unroll
        for (int k = 1; k < NQ; k++) r += ld_agent(&sp2[(size_t)(b * NQ + k) * 1024 + tid]);
        redSm[tid] = r;
    }
    __syncthreads();
    caps_sv(W, redSm, vSm, tid, false, true, out, b);   // final squash -> out
}

extern "C" void kernel_launch(void* const* d_in, const int* in_sizes, int n_in,
                              void* d_out, int out_size, void* d_ws, size_t ws_size,
                              hipStream_t stream) {
    const float* x = (const float*)d_in[0];    // [64,1024,64]
    const float* W = (const float*)d_in[1];    // [16,64,32]
    float* out = (float*)d_out;                // [64,16,32]
    float* ws = (float*)d_ws;

    int*   cnt = (int*)(ws + WS_CNT);
    float* cs  = ws + WS_CS;
    float* sp1 = ws + WS_SP1;
    float* sp2 = ws + WS_SP2;
    float* wv0 = ws + WS_WV0;

    k_colsum<<<dim3(NQ, B_SZ), 256, 0, stream>>>(x, cs, cnt);
    k_iter1<<<B_SZ * NQ, NTHR, 0, stream>>>(x, W, cs, sp1, wv0);
    k_iter2<<<B_SZ * NQ, NTHR, 0, stream>>>(x, W, out, cnt, sp1, sp2, wv0);
}

// Round 20
// 43.953 us; speedup vs baseline: 1.1311x; 1.0319x over previous
//
#include <hip/hip_runtime.h>
#include <math.h>

// Problem constants (fixed by reference setup_inputs)
#define B_SZ 64
#define N_IN 1024
#define IDIM 64
#define NC   16
#define DC   32
#define NQ   4      // blocks per batch
#define QR   256    // rows per block
#define NTHR 1024   // 16 waves
#define XS   68     // xT row stride [n][i]: 68%32=4 -> b128 floor patterns
#define AS   20     // aSmT / pSm / wSm row stride

// Workspace (floats). NOTHING needs zero-init; no atomics, no counters,
// no spin barriers. All cross-block reductions cross kernel boundaries.
//  cs  : [64][4][64]   @ 0       colsum partials (plain)
//  sp1 : [64][4][1024] @ 16384   xs partials iter 1 (plain)
//  sp2 : [64][4][1024] @ 278528  xs partials iter 2 (plain)
//  wv0 : [64][1024]    @ 540672  wv(v0) (plain; q0 writes in K1, read in K2)
#define WS_CS  0
#define WS_SP1 16384
#define WS_SP2 278528
#define WS_WV0 540672

__device__ __forceinline__ float rdlane_f(float v, int l) {
    return __int_as_float(__builtin_amdgcn_readlane(__float_as_int(v), l));
}

// ---- shared building blocks (round-12/17-proven inner code) ----

// stage 256 rows into [n][i] tile: 4 conflict-free ds_write_b128/thread
__device__ __forceinline__ void stage_x(const float* __restrict__ x, float* xT,
                                        int b, int q, int tid) {
    const float4* xb4 = reinterpret_cast<const float4*>(x + ((size_t)b * N_IN + q * QR) * IDIM);
#pragma unroll
    for (int m = 0; m < 4; m++) {
        const int f = tid + m * NTHR;
        const float4 v4 = xb4[f];
        const int n = f >> 4, i0 = (f & 15) * 4;
        *reinterpret_cast<float4*>(&xT[n * XS + i0]) = v4;
    }
}

// routing pass: agreement(b128+readlane) -> softmax(regs) -> xs(readlane) -> val
__device__ __forceinline__ float route_pass(const float* xT, const float* wSm,
                                            float* aSmT, float* pSm,
                                            int tid, int lane, int wave,
                                            int row, int grp, int rq) {
    const float4 wr4 = *reinterpret_cast<const float4*>(&wSm[lane * AS + grp * 4]);
    {   // agreement: caps grp*4..+3 for row; 16 b128 + readlane-fma
        float a0 = 0.f, a1 = 0.f, a2 = 0.f, a3 = 0.f;
#pragma unroll
        for (int iq = 0; iq < 16; iq++) {
            const float4 xv = *reinterpret_cast<const float4*>(&xT[row * XS + iq * 4]);
#pragma unroll
            for (int j = 0; j < 4; j++) {
                const int i = iq * 4 + j;
                const float xc = (j == 0) ? xv.x : (j == 1) ? xv.y
                               : (j == 2) ? xv.z : xv.w;
                a0 += rdlane_f(wr4.x, i) * xc;
                a1 += rdlane_f(wr4.y, i) * xc;
                a2 += rdlane_f(wr4.z, i) * xc;
                a3 += rdlane_f(wr4.w, i) * xc;
            }
        }
        *reinterpret_cast<float4*>(&aSmT[row * AS + grp * 4]) =
            make_float4(a0, a1, a2, a3);
    }
    __syncthreads();
    // softmax over 16 caps per row; cw via uniform grp if-chain (regs only)
    float cw0, cw1, cw2, cw3;
    {
        const float4 q0 = *reinterpret_cast<const float4*>(&aSmT[row * AS + 0]);
        const float4 q1 = *reinterpret_cast<const float4*>(&aSmT[row * AS + 4]);
        const float4 q2 = *reinterpret_cast<const float4*>(&aSmT[row * AS + 8]);
        const float4 q3 = *reinterpret_cast<const float4*>(&aSmT[row * AS + 12]);
        float av[NC] = {q0.x, q0.y, q0.z, q0.w, q1.x, q1.y, q1.z, q1.w,
                        q2.x, q2.y, q2.z, q2.w, q3.x, q3.y, q3.z, q3.w};
        // pairwise max tree (depth 4, v_max3-friendly)
        const float m01 = fmaxf(fmaxf(av[0], av[1]), fmaxf(av[2], av[3]));
        const float m23 = fmaxf(fmaxf(av[4], av[5]), fmaxf(av[6], av[7]));
        const float m45 = fmaxf(fmaxf(av[8], av[9]), fmaxf(av[10], av[11]));
        const float m67 = fmaxf(fmaxf(av[12], av[13]), fmaxf(av[14], av[15]));
        const float mx = fmaxf(fmaxf(m01, m23), fmaxf(m45, m67));
        float ss = 0.f;
#pragma unroll
        for (int k = 0; k < NC; k++) { av[k] = __expf(av[k] - mx); ss += av[k]; }
        const float inv = 1.f / ss;
        if (grp == 0)      { cw0 = av[0];  cw1 = av[1];  cw2 = av[2];  cw3 = av[3];  }
        else if (grp == 1) { cw0 = av[4];  cw1 = av[5];  cw2 = av[6];  cw3 = av[7];  }
        else if (grp == 2) { cw0 = av[8];  cw1 = av[9];  cw2 = av[10]; cw3 = av[11]; }
        else               { cw0 = av[12]; cw1 = av[13]; cw2 = av[14]; cw3 = av[15]; }
        cw0 *= inv; cw1 *= inv; cw2 *= inv; cw3 *= inv;
    }
    // xs: NO sync (reads xT + same-wave regs). wave (grp, rq): caps grp*4..+3,
    // rows rq*64..+63, lane = i; cw for row rq*64+nl lives in lane nl.
    {
        float s0 = 0.f, s1 = 0.f, s2 = 0.f, s3 = 0.f;
#pragma unroll
        for (int nl = 0; nl < 64; nl++) {
            const float xv = xT[(rq * 64 + nl) * XS + lane];   // coalesced b32
            s0 += rdlane_f(cw0, nl) * xv;
            s1 += rdlane_f(cw1, nl) * xv;
            s2 += rdlane_f(cw2, nl) * xv;
            s3 += rdlane_f(cw3, nl) * xv;
        }
        *reinterpret_cast<float4*>(&pSm[(rq * 64 + lane) * AS + grp * 4]) =
            make_float4(s0, s1, s2, s3);
    }
    __syncthreads();
    // reduce the 4 rq partials: thread (c = wave, i = lane) -> val for o = tid
    return pSm[(0 * 64 + lane) * AS + wave] + pSm[(1 * 64 + lane) * AS + wave] +
           pSm[(2 * 64 + lane) * AS + wave] + pSm[(3 * 64 + lane) * AS + wave];
}

// s = red @ W[c] (+scale) -> squash -> vSm (or out)
__device__ __forceinline__ void caps_sv(const float* __restrict__ W, const float* redSm,
                                        float* vSm, int tid, bool modeRed0, bool toOut,
                                        float* __restrict__ outp, int b) {
    if (tid < 512) {
        const int c = tid >> 5, dd = tid & 31;
        const float* Wc = W + c * (IDIM * DC) + dd;
        float s = 0.f;
#pragma unroll 8
        for (int i = 0; i < IDIM; i++) {
            const float rv = modeRed0 ? redSm[i] : redSm[c * 64 + i];
            s += rv * Wc[i * DC];
        }
        if (modeRed0) s *= 0.0625f;
        float n2 = s * s;
#pragma unroll
        for (int m = 16; m >= 1; m >>= 1) n2 += __shfl_xor(n2, m);  // 32-lane half
        const float g = (n2 / (1.f + n2)) / (sqrtf(n2) + 1e-8f);
        if (toOut) outp[b * (NC * DC) + c * DC + dd] = g * s;
        else       vSm[c * 36 + dd] = g * s;
    }
    __syncthreads();
}

__device__ __forceinline__ float caps_wv(const float* __restrict__ W, const float* vSm,
                                         int tid) {
    const int i = tid >> 4, c = tid & 15;   // 64 i x 16 c; out index == tid
    const float4* Wr = reinterpret_cast<const float4*>(W + (size_t)(c * IDIM + i) * DC);
    const float4* vv = reinterpret_cast<const float4*>(&vSm[c * 36]);
    float acc = 0.f;
#pragma unroll
    for (int dq = 0; dq < 8; dq++) {
        const float4 wq = Wr[dq], vq = vv[dq];
        acc += wq.x * vq.x + wq.y * vq.y + wq.z * vq.z + wq.w * vq.w;
    }
    return acc;
}

// ---- K0: colsum partials straight from global (streams x, warms L3)
__global__ __launch_bounds__(256) void k_colsum(const float* __restrict__ x,
                                                float* __restrict__ cs) {
    const int b = blockIdx.y, q = blockIdx.x;
    const int tid = threadIdx.x;
    const float4* xb4 = reinterpret_cast<const float4*>(x + ((size_t)b * N_IN + q * QR) * IDIM);
    float4 s4 = {0.f, 0.f, 0.f, 0.f};
#pragma unroll
    for (int m = 0; m < 16; m++) {
        const float4 v4 = xb4[tid + m * 256];
        s4.x += v4.x; s4.y += v4.y; s4.z += v4.z; s4.w += v4.w;
    }
    __shared__ float red[16][64];
    const int g = tid >> 4, i0 = (tid & 15) * 4;
    red[g][i0 + 0] = s4.x; red[g][i0 + 1] = s4.y;
    red[g][i0 + 2] = s4.z; red[g][i0 + 3] = s4.w;
    __syncthreads();
    if (tid < 64) {
        float r = 0.f;
#pragma unroll
        for (int k = 0; k < 16; k++) r += red[k][tid];
        cs[(b * NQ + q) * 64 + tid] = r;
    }
}

// ---- K1: (cs loads first) + stage -> caps0 -> route1 -> sp1 (all plain)
__global__ __launch_bounds__(NTHR, 1)
void k_iter1(const float* __restrict__ x, const float* __restrict__ W,
             const float* __restrict__ cs, float* __restrict__ sp1,
             float* __restrict__ wv0) {
    const int b = blockIdx.x & 63, q = blockIdx.x >> 6;   // XCD co-location
    const int tid = threadIdx.x, lane = tid & 63, wave = tid >> 6;
    const int row = tid & 255, grp = tid >> 8, rq = wave & 3;

    __shared__ float __align__(16) xT[QR * XS];
    __shared__ float __align__(16) aSmT[QR * AS];
    __shared__ float __align__(16) pSm[4 * 64 * AS];
    __shared__ float __align__(16) wSm[IDIM * AS];
    __shared__ float redSm[NC * IDIM];
    __shared__ float __align__(16) vSm[NC * 36];

    // critical-path loads FIRST (cs -> caps chain), then stage (off-path)
    float csr[NQ];
    if (tid < 64) {
#pragma unroll
        for (int k = 0; k < NQ; k++) csr[k] = cs[(b * NQ + k) * 64 + tid];
    }
    stage_x(x, xT, b, q, tid);                 // L3-warm from K0
    if (tid < 64) redSm[tid] = csr[0] + csr[1] + csr[2] + csr[3];
    __syncthreads();
    caps_sv(W, redSm, vSm, tid, true, false, nullptr, b);
    {
        const float acc = caps_wv(W, vSm, tid);
        wSm[(tid >> 4) * AS + (tid & 15)] = acc;
        if (q == 0) wv0[b * 1024 + tid] = acc;
    }
    __syncthreads();
    const float val = route_pass(xT, wSm, aSmT, pSm, tid, lane, wave, row, grp, rq);
    sp1[(size_t)(b * NQ + q) * 1024 + tid] = val;
}

// ---- K2: (sp1+wv0 loads first) + stage -> caps1 (wv_eff = wv(v1)+wv0) -> route2
__global__ __launch_bounds__(NTHR, 1)
void k_iter2(const float* __restrict__ x, const float* __restrict__ W,
             const float* __restrict__ sp1, float* __restrict__ sp2,
             const float* __restrict__ wv0) {
    const int b = blockIdx.x & 63, q = blockIdx.x >> 6;
    const int tid = threadIdx.x, lane = tid & 63, wave = tid >> 6;
    const int row = tid & 255, grp = tid >> 8, rq = wave & 3;

    __shared__ float __align__(16) xT[QR * XS];
    __shared__ float __align__(16) aSmT[QR * AS];
    __shared__ float __align__(16) pSm[4 * 64 * AS];
    __shared__ float __align__(16) wSm[IDIM * AS];
    __shared__ float redSm[NC * IDIM];
    __shared__ float __align__(16) vSm[NC * 36];

    // critical-path loads FIRST (sp1 -> caps chain; wv0 for wSm tail)
    float spr[NQ];
#pragma unroll
    for (int k = 0; k < NQ; k++) spr[k] = sp1[(size_t)(b * NQ + k) * 1024 + tid];
    const float wv0v = wv0[b * 1024 + tid];
    stage_x(x, xT, b, q, tid);                 // same grid mapping -> L2-resident
    redSm[tid] = spr[0] + spr[1] + spr[2] + spr[3];
    __syncthreads();
    caps_sv(W, redSm, vSm, tid, false, false, nullptr, b);
    wSm[(tid >> 4) * AS + (tid & 15)] = caps_wv(W, vSm, tid) + wv0v;
    __syncthreads();
    const float val = route_pass(xT, wSm, aSmT, pSm, tid, lane, wave, row, grp, rq);
    sp2[(size_t)(b * NQ + q) * 1024 + tid] = val;
}

// ---- K3: reduce sp2 -> final squash -> out
__global__ __launch_bounds__(1024) void k_final(const float* __restrict__ sp2,
                                                const float* __restrict__ W,
                                                float* __restrict__ out) {
    const int b = blockIdx.x, tid = threadIdx.x;
    __shared__ float redSm[NC * IDIM];
    __shared__ float __align__(16) vSm[NC * 36];
    {
        float r = 0.f;
#pragma unroll
        for (int k = 0; k < NQ; k++) r += sp2[(size_t)(b * NQ + k) * 1024 + tid];
        redSm[tid] = r;
    }
    __syncthreads();
    caps_sv(W, redSm, vSm, tid, false, true, out, b);
}

extern "C" void kernel_launch(void* const* d_in, const int* in_sizes, int n_in,
                              void* d_out, int out_size, void* d_ws, size_t ws_size,
                              hipStream_t stream) {
    const float* x = (const float*)d_in[0];    // [64,1024,64]
    const float* W = (const float*)d_in[1];    // [16,64,32]
    float* out = (float*)d_out;                // [64,16,32]
    float* ws = (float*)d_ws;

    float* cs  = ws + WS_CS;
    float* sp1 = ws + WS_SP1;
    float* sp2 = ws + WS_SP2;
    float* wv0 = ws + WS_WV0;

    k_colsum<<<dim3(NQ, B_SZ), 256, 0, stream>>>(x, cs);
    k_iter1<<<B_SZ * NQ, NTHR, 0, stream>>>(x, W, cs, sp1, wv0);
    k_iter2<<<B_SZ * NQ, NTHR, 0, stream>>>(x, W, sp1, sp2, wv0);
    k_final<<<B_SZ, 1024, 0, stream>>>(sp2, W, out);
}